// Round 9
// baseline (337.928 us; speedup 1.0000x reference)
//
#include <hip/hip_runtime.h>
#include <math.h>

#define H 512
#define W 512
#define HW (H*W)
#define NB 4
#define NC 32

// ---------------- 1x1 conv over ODD channels only, float4 ----------------
// (even-channel contribution is accumulated inside k_whmax while it has the data)
__global__ __launch_bounds__(256) void k_sc_odd(const float* __restrict__ color,
                                                const float* __restrict__ wscore,
                                                float* __restrict__ scO) {
    int p4 = blockIdx.x * 256 + threadIdx.x;
    const int NP4 = NB * HW / 4;
    if (p4 >= NP4) return;
    int b = p4 / (HW / 4), i4 = p4 % (HW / 4);
    const float4* base = (const float4*)(color + (size_t)b * NC * HW) + i4;
    float4 acc = make_float4(0.f, 0.f, 0.f, 0.f);
    #pragma unroll
    for (int ci = 0; ci < 16; ++ci) {
        const int c = 2 * ci + 1;
        float4 v = base[(size_t)c * (HW / 4)];
        float wv = wscore[c];
        acc.x = fmaf(v.x, wv, acc.x);
        acc.y = fmaf(v.y, wv, acc.y);
        acc.z = fmaf(v.z, wv, acc.z);
        acc.w = fmaf(v.w, wv, acc.w);
    }
    ((float4*)scO)[p4] = acc;
}

// ---------------- fused avgpool3x3 -> depthwise conv5x5 -> even-channel max ----------------
// 2x4 tile. __launch_bounds__(256,8) forces VGPR<=64 to cross the m69-measured
// occupancy step (waves/CU halves at VGPR=64) — testing the VGPR-residency-cap theory.
__global__ __launch_bounds__(256, 8) void k_whmax(const float* __restrict__ color,
                                                  const float* __restrict__ wbbx,
                                                  const float* __restrict__ wscore,
                                                  float* __restrict__ pw,
                                                  float* __restrict__ scE) {
    const int lane = threadIdx.x;                           // blockDim = (64,4)
    const int x0 = (blockIdx.x * 64 + lane) * 4;            // 0..508, multiple of 4
    const int y0 = (blockIdx.y * 4 + threadIdx.y) * 2;      // 0..510, step 2
    const int bz = blockIdx.z;                              // b*2 + g
    const int b = bz >> 1, g = bz & 1;

    const bool m0 = (x0 >= 4);          // left float4 chunk fully valid?
    const bool m2 = (x0 <= 504);        // right float4 chunk fully valid?
    const int xm4 = m0 ? (x0 - 4) : x0;
    const int xp4 = m2 ? (x0 + 4) : x0;

    float colmask[8];                   // pooled-column validity * 1/9
    #pragma unroll
    for (int j = 0; j < 8; ++j) {
        int cxx = x0 - 2 + j;
        colmask[j] = (cxx >= 0 && cxx < W) ? (1.f / 9.f) : 0.f;
    }

    float wmx[2][4], scacc[2][4];
    #pragma unroll
    for (int ot = 0; ot < 2; ++ot)
        #pragma unroll
        for (int oc = 0; oc < 4; ++oc) { wmx[ot][oc] = -INFINITY; scacc[ot][oc] = 0.f; }

    for (int ci = 0; ci < 8; ++ci) {
        const int c = 2 * (g * 8 + ci);                      // even channels only
        const float* img = color + (size_t)(b * NC + c) * HW;
        const float* wc  = wbbx + c * 25;
        const float wsc  = wscore[c];

        float acc[2][4];
        #pragma unroll
        for (int ot = 0; ot < 2; ++ot)
            #pragma unroll
            for (int oc = 0; oc < 4; ++oc) acc[ot][oc] = 0.f;

        float rs[3][8];   // rolling 3x3-rowsums at pooled cols x0-2..x0+5

        auto loadrs = [&](int r, float* dst, int cot) {
            if (r < 0 || r >= H) {                           // wave-uniform branch
                #pragma unroll
                for (int j = 0; j < 8; ++j) dst[j] = 0.f;
                return;
            }
            const float* row = img + (size_t)r * W;
            float4 c0 = *(const float4*)(row + xm4);
            float4 c1 = *(const float4*)(row + x0);
            float4 c2 = *(const float4*)(row + xp4);
            if (!m0) c0 = make_float4(0.f, 0.f, 0.f, 0.f);
            if (!m2) c2 = make_float4(0.f, 0.f, 0.f, 0.f);
            if (cot >= 0) {                                  // compile-time after unroll
                scacc[cot][0] = fmaf(c1.x, wsc, scacc[cot][0]);
                scacc[cot][1] = fmaf(c1.y, wsc, scacc[cot][1]);
                scacc[cot][2] = fmaf(c1.z, wsc, scacc[cot][2]);
                scacc[cot][3] = fmaf(c1.w, wsc, scacc[cot][3]);
            }
            float v[12];
            v[0] = c0.x; v[1] = c0.y; v[2]  = c0.z; v[3]  = c0.w;
            v[4] = c1.x; v[5] = c1.y; v[6]  = c1.z; v[7]  = c1.w;
            v[8] = c2.x; v[9] = c2.y; v[10] = c2.z; v[11] = c2.w;
            #pragma unroll
            for (int j = 0; j < 8; ++j) dst[j] = v[j + 1] + v[j + 2] + v[j + 3];
        };

        loadrs(y0 - 3, rs[0], -1);
        loadrs(y0 - 2, rs[1], -1);

        #pragma unroll
        for (int it = 0; it < 6; ++it) {                     // pooled rows y0-2 .. y0+3
            const int sA = it % 3, sB = (it + 1) % 3, sC = (it + 2) % 3;
            loadrs(y0 - 1 + it, rs[sC], (it >= 1 && it <= 2) ? it - 1 : -1);
            const int cr = y0 - 2 + it;
            float col[8];
            if (cr >= 0 && cr < H) {                         // wave-uniform
                #pragma unroll
                for (int j = 0; j < 8; ++j)
                    col[j] = (rs[sA][j] + rs[sB][j] + rs[sC][j]) * colmask[j];
            } else {
                #pragma unroll
                for (int j = 0; j < 8; ++j) col[j] = 0.f;
            }
            #pragma unroll
            for (int ot = 0; ot < 2; ++ot) {
                if (ot >= it - 4 && ot <= it) {              // compile-time after unroll
                    const int kr = it - ot;                  // weight row
                    #pragma unroll
                    for (int oc = 0; oc < 4; ++oc) {
                        float a = acc[ot][oc];
                        #pragma unroll
                        for (int d = 0; d < 5; ++d)
                            a = fmaf(col[oc + d], wc[kr * 5 + d], a);
                        acc[ot][oc] = a;
                    }
                }
            }
        }

        #pragma unroll
        for (int ot = 0; ot < 2; ++ot)
            #pragma unroll
            for (int oc = 0; oc < 4; ++oc)
                wmx[ot][oc] = fmaxf(wmx[ot][oc], acc[ot][oc]);
    }

    size_t off = ((size_t)g * NB + b) * HW + (size_t)y0 * W + x0;
    #pragma unroll
    for (int ot = 0; ot < 2; ++ot) {
        *(float4*)(pw + off + (size_t)ot * W)  = make_float4(wmx[ot][0], wmx[ot][1], wmx[ot][2], wmx[ot][3]);
        *(float4*)(scE + off + (size_t)ot * W) = make_float4(scacc[ot][0], scacc[ot][1], scacc[ot][2], scacc[ot][3]);
    }
}

// ---------------- fused: sum sc partials -> avgpool5 -> avgpool3 -> sigmoid+top10 ----------------
// One 8-row x 512-col output stripe per block. Separable box sums in LDS.
__global__ __launch_bounds__(256) void k_poolcand(const float* __restrict__ scE,
                                                  const float* __restrict__ scO,
                                                  float* __restrict__ score_map,
                                                  float* __restrict__ cand) {
    const int sb = blockIdx.x;           // 0..63  (stripe)
    const int b  = blockIdx.y;
    const int t  = threadIdx.x;
    const int y0 = sb * 8;

    __shared__ float A[14][512];         // sc rows y0-3..y0+10, later P5 rows y0-1..y0+8
    __shared__ float Bf[14][512];        // T1 rows,            later T2 rows

    // load sc = scE0 + scE1 + scO (zero outside)
    for (int r = 0; r < 14; ++r) {
        int gy = y0 - 3 + r;
        for (int xx = t; xx < 512; xx += 256) {
            float v = 0.f;
            if (gy >= 0 && gy < H) {
                size_t idx = (size_t)b * HW + (size_t)gy * W + xx;
                v = scE[idx] + scE[(size_t)NB * HW + idx] + scO[idx];
            }
            A[r][xx] = v;
        }
    }
    __syncthreads();
    // T1 = rowsum5(sc), x zero-pad
    for (int r = 0; r < 14; ++r)
        for (int xx = t; xx < 512; xx += 256) {
            float s = 0.f;
            #pragma unroll
            for (int d = -2; d <= 2; ++d) {
                int x2 = xx + d;
                if (x2 >= 0 && x2 < 512) s += A[r][x2];
            }
            Bf[r][xx] = s;
        }
    __syncthreads();
    // P5 rows y0-1..y0+8 (zero row if OOB) -> A[0..9]
    for (int r2 = 0; r2 < 10; ++r2) {
        int gy = y0 - 1 + r2;
        for (int xx = t; xx < 512; xx += 256) {
            float s = 0.f;
            if (gy >= 0 && gy < H) {
                #pragma unroll
                for (int d = 0; d < 5; ++d) s += Bf[r2 + d][xx];
                s *= (1.f / 25.f);
            }
            A[r2][xx] = s;
        }
    }
    __syncthreads();
    // T2 = rowsum3(P5), x zero-pad -> Bf[0..9]
    for (int r2 = 0; r2 < 10; ++r2)
        for (int xx = t; xx < 512; xx += 256) {
            float s = 0.f;
            #pragma unroll
            for (int d = -1; d <= 1; ++d) {
                int x2 = xx + d;
                if (x2 >= 0 && x2 < 512) s += A[r2][x2];
            }
            Bf[r2][xx] = s;
        }
    __syncthreads();

    // score rows y0..y0+7 = colsum3(T2)/9 ; write + sigmoid + thread top-10
    float top[10];
    #pragma unroll
    for (int k = 0; k < 10; ++k) top[k] = -INFINITY;

    for (int r3 = 0; r3 < 8; ++r3) {
        for (int xx = t; xx < 512; xx += 256) {
            float sv = (Bf[r3][xx] + Bf[r3 + 1][xx] + Bf[r3 + 2][xx]) * (1.f / 9.f);
            score_map[(size_t)b * HW + (size_t)(y0 + r3) * W + xx] = sv;
            float s = 1.f / (1.f + expf(-sv));
            if (s > top[9]) {
                top[9] = s;
                #pragma unroll
                for (int k = 9; k > 0; --k)
                    if (top[k] > top[k - 1]) { float tmp = top[k - 1]; top[k - 1] = top[k]; top[k] = tmp; }
            }
        }
    }

    // block top-10 reduction
    __shared__ float sv_[256];
    __shared__ int   si_[256];
    __shared__ int   swin;
    int ptr = 0;
    for (int r = 0; r < 10; ++r) {
        sv_[t] = (ptr < 10) ? top[ptr] : -INFINITY;
        si_[t] = t;
        __syncthreads();
        for (int off = 128; off > 0; off >>= 1) {
            if (t < off && sv_[t + off] > sv_[t]) { sv_[t] = sv_[t + off]; si_[t] = si_[t + off]; }
            __syncthreads();
        }
        if (t == 0) { cand[((size_t)b * 64 + sb) * 10 + r] = sv_[0]; swin = si_[0]; }
        __syncthreads();
        if (t == swin) ptr++;
        __syncthreads();
    }
}

// ---------------- 10th-largest over 640 candidates (tie-robust rank count) ----------------
__global__ __launch_bounds__(256) void k_v10(const float* __restrict__ cand, float* __restrict__ v10) {
    int b = blockIdx.x, t = threadIdx.x;
    __shared__ float c[640];
    for (int j = t; j < 640; j += 256) c[j] = cand[b * 640 + j];
    __syncthreads();
    for (int j = t; j < 640; j += 256) {
        float v = c[j];
        int gt = 0, eq = 0;
        for (int k = 0; k < 640; ++k) { gt += (c[k] > v); eq += (c[k] == v); }
        if (gt <= 9 && gt + eq >= 10) v10[b] = v;
    }
}

// ---------------- final decode ----------------
__global__ __launch_bounds__(256) void k_final(const float* __restrict__ sc,
                                               const float* __restrict__ pw,
                                               const float* __restrict__ v10,
                                               float* __restrict__ outbuf,
                                               float* __restrict__ mbuf) {
    int p = blockIdx.x * 256 + threadIdx.x;
    if (p >= NB * HW) return;
    int b = p / HW, i = p % HW;
    float scv = sc[p];
    float s   = 1.f / (1.f + expf(-scv));          // same formula as k_poolcand -> identical bits
    float s10 = v10[b];
    bool  m   = (s >= s10 && s > 0.6f) || (s > 0.9f);
    // reference quirk: w = channel0 (sc), h = channel1 (wmax)
    float wmv = fmaxf(pw[(size_t)b * HW + i], pw[((size_t)NB + b) * HW + i]);
    float wv = expf(scv) * 10.f;
    float hv = expf(wmv) * 10.f;
    float xs = (float)(i & (W - 1));
    float ys = (float)(i >> 9);
    float o0 = 0.f, o1 = 0.f, o2 = 0.f, o3 = 0.f, o4 = 0.f;
    if (m) {
        o0 = s;
        o1 = floorf(xs - wv);
        o2 = floorf(ys - hv);
        o3 = ceilf(xs + wv);
        o4 = ceilf(ys + hv);
    }
    size_t ob = (size_t)p * 5;
    outbuf[ob + 0] = o0; outbuf[ob + 1] = o1; outbuf[ob + 2] = o2;
    outbuf[ob + 3] = o3; outbuf[ob + 4] = o4;
    mbuf[p] = m ? 1.f : 0.f;
}

extern "C" void kernel_launch(void* const* d_in, const int* in_sizes, int n_in,
                              void* d_out, int out_size, void* d_ws, size_t ws_size,
                              hipStream_t stream) {
    // inputs: mask (unused), color, w_bbx, w_score
    const float* color  = (const float*)d_in[1];
    const float* wbbx   = (const float*)d_in[2];
    const float* wscore = (const float*)d_in[3];

    float* out       = (float*)d_out;
    float* score_map = out;                          // 1048576
    float* outbuf    = out + 1048576;                // 5242880
    float* mbuf      = out + 1048576 + 5242880;      // 1048576

    float* ws   = (float*)d_ws;
    float* pw   = ws;                      // 2 * NB*HW = 2097152
    float* scE  = ws + 2 * 1048576;        // 2 * NB*HW = 2097152
    float* scO  = ws + 4 * 1048576;        // NB*HW    = 1048576
    float* cand = ws + 5 * 1048576;        // 4*640 = 2560
    float* v10  = cand + 2560;             // 4

    k_whmax    <<<dim3(2, 64, NB * 2), dim3(64, 4, 1), 0, stream>>>(color, wbbx, wscore, pw, scE);
    k_sc_odd   <<<(NB * HW / 4 + 255) / 256, 256, 0, stream>>>(color, wscore, scO);
    k_poolcand <<<dim3(64, NB), 256, 0, stream>>>(scE, scO, score_map, cand);
    k_v10      <<<4, 256, 0, stream>>>(cand, v10);
    k_final    <<<(NB * HW + 255) / 256, 256, 0, stream>>>(score_map, pw, v10, outbuf, mbuf);
}

// Round 10
// 163.300 us; speedup vs baseline: 2.0694x; 2.0694x over previous
//
#include <hip/hip_runtime.h>
#include <math.h>

#define H 512
#define W 512
#define HW (H*W)
#define NB 4
#define NC 32

// ---------------- 1x1 conv over ODD channels only, float4 ----------------
__global__ __launch_bounds__(256) void k_sc_odd(const float* __restrict__ color,
                                                const float* __restrict__ wscore,
                                                float* __restrict__ scO) {
    int p4 = blockIdx.x * 256 + threadIdx.x;
    const int NP4 = NB * HW / 4;
    if (p4 >= NP4) return;
    int b = p4 / (HW / 4), i4 = p4 % (HW / 4);
    const float4* base = (const float4*)(color + (size_t)b * NC * HW) + i4;
    float4 acc = make_float4(0.f, 0.f, 0.f, 0.f);
    #pragma unroll
    for (int ci = 0; ci < 16; ++ci) {
        const int c = 2 * ci + 1;
        float4 v = base[(size_t)c * (HW / 4)];
        float wv = wscore[c];
        acc.x = fmaf(v.x, wv, acc.x);
        acc.y = fmaf(v.y, wv, acc.y);
        acc.z = fmaf(v.z, wv, acc.z);
        acc.w = fmaf(v.w, wv, acc.w);
    }
    ((float4*)scO)[p4] = acc;
}

// ---------------- fused avgpool3x3 -> depthwise conv5x5 -> even-channel max ----------------
// 4x4 tile (best per-wave efficiency, R6). CPG channels per block; NG=16/CPG groups
// via blockIdx.z -> more blocks/CU WITHOUT extra work (channels independent, no halo dup).
// NO register forcing (R9: forcing VGPR<=64 -> 32 VGPR + 430MB spill traffic).
template<int CPG>
__global__ __launch_bounds__(256) void k_whmax(const float* __restrict__ color,
                                               const float* __restrict__ wbbx,
                                               const float* __restrict__ wscore,
                                               float* __restrict__ pw,
                                               float* __restrict__ scE) {
    constexpr int NG = 16 / CPG;
    const int lane = threadIdx.x;                           // blockDim = (64,4)
    const int x0 = (blockIdx.x * 64 + lane) * 4;            // 0..508, multiple of 4
    const int y0 = (blockIdx.y * 4 + threadIdx.y) * 4;      // 0..508
    const int bz = blockIdx.z;                              // b*NG + g
    const int b = bz / NG, g = bz % NG;

    const bool m0 = (x0 >= 4);          // left float4 chunk fully valid?
    const bool m2 = (x0 <= 504);        // right float4 chunk fully valid?
    const int xm4 = m0 ? (x0 - 4) : x0;
    const int xp4 = m2 ? (x0 + 4) : x0;

    float colmask[8];                   // pooled-column validity * 1/9
    #pragma unroll
    for (int j = 0; j < 8; ++j) {
        int cxx = x0 - 2 + j;
        colmask[j] = (cxx >= 0 && cxx < W) ? (1.f / 9.f) : 0.f;
    }

    float wmx[4][4], scacc[4][4];
    #pragma unroll
    for (int ot = 0; ot < 4; ++ot)
        #pragma unroll
        for (int oc = 0; oc < 4; ++oc) { wmx[ot][oc] = -INFINITY; scacc[ot][oc] = 0.f; }

    for (int ci = 0; ci < CPG; ++ci) {
        const int c = 2 * (g * CPG + ci);                    // even channels only
        const float* img = color + (size_t)(b * NC + c) * HW;
        const float* wc  = wbbx + c * 25;
        const float wsc  = wscore[c];

        float acc[4][4];
        #pragma unroll
        for (int ot = 0; ot < 4; ++ot)
            #pragma unroll
            for (int oc = 0; oc < 4; ++oc) acc[ot][oc] = 0.f;

        float rs[3][8];   // rolling 3x3-rowsums at pooled cols x0-2..x0+5

        auto loadrs = [&](int r, float* dst, int cot) {
            if (r < 0 || r >= H) {                           // wave-uniform branch
                #pragma unroll
                for (int j = 0; j < 8; ++j) dst[j] = 0.f;
                return;
            }
            const float* row = img + (size_t)r * W;
            float4 c0 = *(const float4*)(row + xm4);
            float4 c1 = *(const float4*)(row + x0);
            float4 c2 = *(const float4*)(row + xp4);
            if (!m0) c0 = make_float4(0.f, 0.f, 0.f, 0.f);
            if (!m2) c2 = make_float4(0.f, 0.f, 0.f, 0.f);
            if (cot >= 0) {                                  // compile-time after unroll
                scacc[cot][0] = fmaf(c1.x, wsc, scacc[cot][0]);
                scacc[cot][1] = fmaf(c1.y, wsc, scacc[cot][1]);
                scacc[cot][2] = fmaf(c1.z, wsc, scacc[cot][2]);
                scacc[cot][3] = fmaf(c1.w, wsc, scacc[cot][3]);
            }
            float v[12];
            v[0] = c0.x; v[1] = c0.y; v[2]  = c0.z; v[3]  = c0.w;
            v[4] = c1.x; v[5] = c1.y; v[6]  = c1.z; v[7]  = c1.w;
            v[8] = c2.x; v[9] = c2.y; v[10] = c2.z; v[11] = c2.w;
            #pragma unroll
            for (int j = 0; j < 8; ++j) dst[j] = v[j + 1] + v[j + 2] + v[j + 3];
        };

        loadrs(y0 - 3, rs[0], -1);
        loadrs(y0 - 2, rs[1], -1);

        #pragma unroll
        for (int it = 0; it < 8; ++it) {                     // pooled rows y0-2 .. y0+5
            const int sA = it % 3, sB = (it + 1) % 3, sC = (it + 2) % 3;
            loadrs(y0 - 1 + it, rs[sC], (it >= 1 && it <= 4) ? it - 1 : -1);
            const int cr = y0 - 2 + it;
            float col[8];
            if (cr >= 0 && cr < H) {                         // wave-uniform
                #pragma unroll
                for (int j = 0; j < 8; ++j)
                    col[j] = (rs[sA][j] + rs[sB][j] + rs[sC][j]) * colmask[j];
            } else {
                #pragma unroll
                for (int j = 0; j < 8; ++j) col[j] = 0.f;
            }
            #pragma unroll
            for (int ot = 0; ot < 4; ++ot) {
                if (ot >= it - 4 && ot <= it) {              // compile-time after unroll
                    const int kr = it - ot;                  // weight row
                    #pragma unroll
                    for (int oc = 0; oc < 4; ++oc) {
                        float a = acc[ot][oc];
                        #pragma unroll
                        for (int d = 0; d < 5; ++d)
                            a = fmaf(col[oc + d], wc[kr * 5 + d], a);
                        acc[ot][oc] = a;
                    }
                }
            }
        }

        #pragma unroll
        for (int ot = 0; ot < 4; ++ot)
            #pragma unroll
            for (int oc = 0; oc < 4; ++oc)
                wmx[ot][oc] = fmaxf(wmx[ot][oc], acc[ot][oc]);
    }

    size_t off = ((size_t)g * NB + b) * HW + (size_t)y0 * W + x0;
    #pragma unroll
    for (int ot = 0; ot < 4; ++ot) {
        *(float4*)(pw + off + (size_t)ot * W)  = make_float4(wmx[ot][0], wmx[ot][1], wmx[ot][2], wmx[ot][3]);
        *(float4*)(scE + off + (size_t)ot * W) = make_float4(scacc[ot][0], scacc[ot][1], scacc[ot][2], scacc[ot][3]);
    }
}

// ---------------- fused: sum sc partials -> avgpool5 -> avgpool3 -> sigmoid+top10 ----------------
__global__ __launch_bounds__(256) void k_poolcand(const float* __restrict__ scE,
                                                  const float* __restrict__ scO,
                                                  float* __restrict__ score_map,
                                                  float* __restrict__ cand,
                                                  int ng) {
    const int sb = blockIdx.x;           // 0..63  (stripe)
    const int b  = blockIdx.y;
    const int t  = threadIdx.x;
    const int y0 = sb * 8;

    __shared__ float A[14][512];         // sc rows y0-3..y0+10, later P5 rows y0-1..y0+8
    __shared__ float Bf[14][512];        // T1 rows,            later T2 rows

    // load sc = sum_g scE[g] + scO (zero outside)
    for (int r = 0; r < 14; ++r) {
        int gy = y0 - 3 + r;
        for (int xx = t; xx < 512; xx += 256) {
            float v = 0.f;
            if (gy >= 0 && gy < H) {
                size_t idx = (size_t)b * HW + (size_t)gy * W + xx;
                v = scO[idx];
                for (int gi = 0; gi < ng; ++gi) v += scE[(size_t)gi * NB * HW + idx];
            }
            A[r][xx] = v;
        }
    }
    __syncthreads();
    // T1 = rowsum5(sc), x zero-pad
    for (int r = 0; r < 14; ++r)
        for (int xx = t; xx < 512; xx += 256) {
            float s = 0.f;
            #pragma unroll
            for (int d = -2; d <= 2; ++d) {
                int x2 = xx + d;
                if (x2 >= 0 && x2 < 512) s += A[r][x2];
            }
            Bf[r][xx] = s;
        }
    __syncthreads();
    // P5 rows y0-1..y0+8 (zero row if OOB) -> A[0..9]
    for (int r2 = 0; r2 < 10; ++r2) {
        int gy = y0 - 1 + r2;
        for (int xx = t; xx < 512; xx += 256) {
            float s = 0.f;
            if (gy >= 0 && gy < H) {
                #pragma unroll
                for (int d = 0; d < 5; ++d) s += Bf[r2 + d][xx];
                s *= (1.f / 25.f);
            }
            A[r2][xx] = s;
        }
    }
    __syncthreads();
    // T2 = rowsum3(P5), x zero-pad -> Bf[0..9]
    for (int r2 = 0; r2 < 10; ++r2)
        for (int xx = t; xx < 512; xx += 256) {
            float s = 0.f;
            #pragma unroll
            for (int d = -1; d <= 1; ++d) {
                int x2 = xx + d;
                if (x2 >= 0 && x2 < 512) s += A[r2][x2];
            }
            Bf[r2][xx] = s;
        }
    __syncthreads();

    // score rows y0..y0+7 = colsum3(T2)/9 ; write + sigmoid + thread top-10
    float top[10];
    #pragma unroll
    for (int k = 0; k < 10; ++k) top[k] = -INFINITY;

    for (int r3 = 0; r3 < 8; ++r3) {
        for (int xx = t; xx < 512; xx += 256) {
            float sv = (Bf[r3][xx] + Bf[r3 + 1][xx] + Bf[r3 + 2][xx]) * (1.f / 9.f);
            score_map[(size_t)b * HW + (size_t)(y0 + r3) * W + xx] = sv;
            float s = 1.f / (1.f + expf(-sv));
            if (s > top[9]) {
                top[9] = s;
                #pragma unroll
                for (int k = 9; k > 0; --k)
                    if (top[k] > top[k - 1]) { float tmp = top[k - 1]; top[k - 1] = top[k]; top[k] = tmp; }
            }
        }
    }

    // block top-10 reduction
    __shared__ float sv_[256];
    __shared__ int   si_[256];
    __shared__ int   swin;
    int ptr = 0;
    for (int r = 0; r < 10; ++r) {
        sv_[t] = (ptr < 10) ? top[ptr] : -INFINITY;
        si_[t] = t;
        __syncthreads();
        for (int off = 128; off > 0; off >>= 1) {
            if (t < off && sv_[t + off] > sv_[t]) { sv_[t] = sv_[t + off]; si_[t] = si_[t + off]; }
            __syncthreads();
        }
        if (t == 0) { cand[((size_t)b * 64 + sb) * 10 + r] = sv_[0]; swin = si_[0]; }
        __syncthreads();
        if (t == swin) ptr++;
        __syncthreads();
    }
}

// ---------------- 10th-largest over 640 candidates (tie-robust rank count) ----------------
__global__ __launch_bounds__(256) void k_v10(const float* __restrict__ cand, float* __restrict__ v10) {
    int b = blockIdx.x, t = threadIdx.x;
    __shared__ float c[640];
    for (int j = t; j < 640; j += 256) c[j] = cand[b * 640 + j];
    __syncthreads();
    for (int j = t; j < 640; j += 256) {
        float v = c[j];
        int gt = 0, eq = 0;
        for (int k = 0; k < 640; ++k) { gt += (c[k] > v); eq += (c[k] == v); }
        if (gt <= 9 && gt + eq >= 10) v10[b] = v;
    }
}

// ---------------- final decode ----------------
__global__ __launch_bounds__(256) void k_final(const float* __restrict__ sc,
                                               const float* __restrict__ pw,
                                               const float* __restrict__ v10,
                                               float* __restrict__ outbuf,
                                               float* __restrict__ mbuf,
                                               int ng) {
    int p = blockIdx.x * 256 + threadIdx.x;
    if (p >= NB * HW) return;
    int b = p / HW, i = p % HW;
    float scv = sc[p];
    float s   = 1.f / (1.f + expf(-scv));          // same formula as k_poolcand -> identical bits
    float s10 = v10[b];
    bool  m   = (s >= s10 && s > 0.6f) || (s > 0.9f);
    // reference quirk: w = channel0 (sc), h = channel1 (wmax)
    size_t idx = (size_t)b * HW + i;
    float wmv = pw[idx];
    for (int gi = 1; gi < ng; ++gi) wmv = fmaxf(wmv, pw[(size_t)gi * NB * HW + idx]);
    float wv = expf(scv) * 10.f;
    float hv = expf(wmv) * 10.f;
    float xs = (float)(i & (W - 1));
    float ys = (float)(i >> 9);
    float o0 = 0.f, o1 = 0.f, o2 = 0.f, o3 = 0.f, o4 = 0.f;
    if (m) {
        o0 = s;
        o1 = floorf(xs - wv);
        o2 = floorf(ys - hv);
        o3 = ceilf(xs + wv);
        o4 = ceilf(ys + hv);
    }
    size_t ob = (size_t)p * 5;
    outbuf[ob + 0] = o0; outbuf[ob + 1] = o1; outbuf[ob + 2] = o2;
    outbuf[ob + 3] = o3; outbuf[ob + 4] = o4;
    mbuf[p] = m ? 1.f : 0.f;
}

extern "C" void kernel_launch(void* const* d_in, const int* in_sizes, int n_in,
                              void* d_out, int out_size, void* d_ws, size_t ws_size,
                              hipStream_t stream) {
    // inputs: mask (unused), color, w_bbx, w_score
    const float* color  = (const float*)d_in[1];
    const float* wbbx   = (const float*)d_in[2];
    const float* wscore = (const float*)d_in[3];

    float* out       = (float*)d_out;
    float* score_map = out;                          // 1048576
    float* outbuf    = out + 1048576;                // 5242880
    float* mbuf      = out + 1048576 + 5242880;      // 1048576

    // NG=4 needs (4+4+1)*4MB + eps ~= 36.1 MB of ws; fall back to NG=2 if scarce.
    const bool big = ws_size >= (size_t)40 * 1024 * 1024;
    const int ng = big ? 4 : 2;

    float* ws   = (float*)d_ws;
    float* pw   = ws;                                   // ng * NB*HW
    float* scE  = ws + (size_t)ng * NB * HW;            // ng * NB*HW
    float* scO  = ws + (size_t)2 * ng * NB * HW;        // NB*HW
    float* cand = ws + (size_t)(2 * ng + 1) * NB * HW;  // 4*640
    float* v10  = cand + 2560;                          // 4

    if (big) k_whmax<4><<<dim3(2, 32, NB * 4), dim3(64, 4, 1), 0, stream>>>(color, wbbx, wscore, pw, scE);
    else     k_whmax<8><<<dim3(2, 32, NB * 2), dim3(64, 4, 1), 0, stream>>>(color, wbbx, wscore, pw, scE);
    k_sc_odd   <<<(NB * HW / 4 + 255) / 256, 256, 0, stream>>>(color, wscore, scO);
    k_poolcand <<<dim3(64, NB), 256, 0, stream>>>(scE, scO, score_map, cand, ng);
    k_v10      <<<4, 256, 0, stream>>>(cand, v10);
    k_final    <<<(NB * HW + 255) / 256, 256, 0, stream>>>(score_map, pw, v10, outbuf, mbuf, ng);
}

// Round 13
// 138.943 us; speedup vs baseline: 2.4321x; 1.1753x over previous
//
#include <hip/hip_runtime.h>
#include <math.h>

#define H 512
#define W 512
#define HW (H*W)
#define NB 4
#define NC 32

// ---------------- 1x1 conv over ALL 32 channels, float4 (R4-proven) ----------------
__global__ __launch_bounds__(256) void k_sc(const float* __restrict__ color,
                                            const float* __restrict__ wscore,
                                            float* __restrict__ sc) {
    int p4 = blockIdx.x * 256 + threadIdx.x;
    const int NP4 = NB * HW / 4;
    if (p4 >= NP4) return;
    int b = p4 / (HW / 4), i4 = p4 % (HW / 4);
    const float4* base = (const float4*)(color + (size_t)b * NC * HW) + i4;
    float4 acc = make_float4(0.f, 0.f, 0.f, 0.f);
    #pragma unroll
    for (int c = 0; c < NC; ++c) {
        float4 v = base[(size_t)c * (HW / 4)];
        float wv = wscore[c];
        acc.x = fmaf(v.x, wv, acc.x);
        acc.y = fmaf(v.y, wv, acc.y);
        acc.z = fmaf(v.z, wv, acc.z);
        acc.w = fmaf(v.w, wv, acc.w);
    }
    ((float4*)sc)[p4] = acc;
}

// ---------------- LDS-staged: avgpool3x3 -> depthwise conv5x5 -> even-channel max ----------------
// Registers hold only accumulators (target VGPR <= 64 per the measured waves/CU ~ 512/VGPR law).
// Block: 128x32 output tile, 4 even channels (g selects group of 4); partial max -> pw[g].
// A = raw tile (zero-padded), P = pooled tile (1/9 + conv zero-padding folded). SGPR weights.
__global__ __launch_bounds__(256) void k_whmax(const float* __restrict__ color,
                                               const float* __restrict__ wbbx,
                                               float* __restrict__ pw) {
    __shared__ float A[38][140];   // rows Y0-3..Y0+34, cols X0-4..X0+135
    __shared__ float P[36][136];   // rows Y0-2..Y0+33, cols X0-2..X0+133

    const int t  = threadIdx.x;
    const int X0 = blockIdx.x * 128;
    const int Y0 = blockIdx.y * 32;
    const int b  = blockIdx.z >> 2;
    const int g  = blockIdx.z & 3;
    const int tx = t & 31, ty = t >> 5;          // 32 x-threads (4 cols), 8 y-threads (4 rows)

    float wmx[4][4];
    #pragma unroll
    for (int ol = 0; ol < 4; ++ol)
        #pragma unroll
        for (int cc = 0; cc < 4; ++cc) wmx[ol][cc] = -INFINITY;

    for (int ci = 0; ci < 4; ++ci) {
        const int c = 2 * (g * 4 + ci);                      // even channels only
        const float* img = color + ((size_t)b * NC + c) * HW;
        const float* wc  = wbbx + c * 25;                    // uniform -> SGPR loads

        // ---- stage A (zero-padded) ----
        for (int u = t; u < 38 * 35; u += 256) {
            int r = u / 35, c4 = u % 35;
            int gy = Y0 - 3 + r, gx0 = X0 - 4 + c4 * 4;
            float4 v = make_float4(0.f, 0.f, 0.f, 0.f);
            if (gy >= 0 && gy < H) {
                if (gx0 >= 0 && gx0 <= W - 4) {
                    v = *(const float4*)(img + (size_t)gy * W + gx0);
                } else {
                    float e0 = (gx0 + 0 >= 0 && gx0 + 0 < W) ? img[(size_t)gy * W + gx0 + 0] : 0.f;
                    float e1 = (gx0 + 1 >= 0 && gx0 + 1 < W) ? img[(size_t)gy * W + gx0 + 1] : 0.f;
                    float e2 = (gx0 + 2 >= 0 && gx0 + 2 < W) ? img[(size_t)gy * W + gx0 + 2] : 0.f;
                    float e3 = (gx0 + 3 >= 0 && gx0 + 3 < W) ? img[(size_t)gy * W + gx0 + 3] : 0.f;
                    v = make_float4(e0, e1, e2, e3);
                }
            }
            *(float4*)&A[r][c4 * 4] = v;
        }
        __syncthreads();   // A ready; also guarantees prev channel's phase3 (P readers) done

        // ---- phase 2: P = box3x3(A)/9, with conv zero-padding outside [0,512) ----
        for (int u = t; u < 36 * 17; u += 256) {
            int pr = u / 17, ch = u % 17;
            int j0 = ch * 8;                                  // P cols j0..j0+7 (<=135)
            int gyP = Y0 - 2 + pr;
            float p[8];
            if (gyP >= 0 && gyP < H) {
                float vs[12];
                #pragma unroll
                for (int q = 0; q < 3; ++q) {
                    float4 x0 = *(const float4*)&A[pr + 0][j0 + q * 4];
                    float4 x1 = *(const float4*)&A[pr + 1][j0 + q * 4];
                    float4 x2 = *(const float4*)&A[pr + 2][j0 + q * 4];
                    vs[q * 4 + 0] = x0.x + x1.x + x2.x;
                    vs[q * 4 + 1] = x0.y + x1.y + x2.y;
                    vs[q * 4 + 2] = x0.z + x1.z + x2.z;
                    vs[q * 4 + 3] = x0.w + x1.w + x2.w;
                }
                #pragma unroll
                for (int jj = 0; jj < 8; ++jj) {
                    int gxP = X0 - 2 + j0 + jj;
                    float s = (vs[jj + 1] + vs[jj + 2] + vs[jj + 3]) * (1.f / 9.f);
                    p[jj] = (gxP >= 0 && gxP < W) ? s : 0.f;
                }
            } else {
                #pragma unroll
                for (int jj = 0; jj < 8; ++jj) p[jj] = 0.f;
            }
            *(float4*)&P[pr][j0 + 0] = make_float4(p[0], p[1], p[2], p[3]);
            *(float4*)&P[pr][j0 + 4] = make_float4(p[4], p[5], p[6], p[7]);
        }
        __syncthreads();

        // ---- phase 3: conv5x5 from P (SGPR weights), fmax into wmx ----
        float acc[4][4];
        #pragma unroll
        for (int ol = 0; ol < 4; ++ol)
            #pragma unroll
            for (int cc = 0; cc < 4; ++cc) acc[ol][cc] = 0.f;

        #pragma unroll
        for (int pr8 = 0; pr8 < 8; ++pr8) {
            int pr = ty * 4 + pr8;
            float4 q0 = *(const float4*)&P[pr][tx * 4 + 0];
            float4 q1 = *(const float4*)&P[pr][tx * 4 + 4];
            float c8[8] = {q0.x, q0.y, q0.z, q0.w, q1.x, q1.y, q1.z, q1.w};
            #pragma unroll
            for (int ol = 0; ol < 4; ++ol) {
                const int ky = pr8 - ol;
                if (ky >= 0 && ky <= 4) {                     // compile-time after unroll
                    #pragma unroll
                    for (int cc = 0; cc < 4; ++cc) {
                        float a = acc[ol][cc];
                        #pragma unroll
                        for (int kx = 0; kx < 5; ++kx)
                            a = fmaf(c8[cc + kx], wc[ky * 5 + kx], a);
                        acc[ol][cc] = a;
                    }
                }
            }
        }
        #pragma unroll
        for (int ol = 0; ol < 4; ++ol)
            #pragma unroll
            for (int cc = 0; cc < 4; ++cc)
                wmx[ol][cc] = fmaxf(wmx[ol][cc], acc[ol][cc]);
    }

    float* obase = pw + ((size_t)g * NB + b) * HW + (size_t)(Y0 + ty * 4) * W + X0 + tx * 4;
    #pragma unroll
    for (int ol = 0; ol < 4; ++ol)
        *(float4*)(obase + (size_t)ol * W) = make_float4(wmx[ol][0], wmx[ol][1], wmx[ol][2], wmx[ol][3]);
}

// ---------------- fused: avgpool5 -> avgpool3 -> sigmoid+top10 (single sc input) ----------------
__global__ __launch_bounds__(256) void k_poolcand(const float* __restrict__ sc,
                                                  float* __restrict__ score_map,
                                                  float* __restrict__ cand) {
    const int sb = blockIdx.x;           // 0..63  (stripe)
    const int b  = blockIdx.y;
    const int t  = threadIdx.x;
    const int y0 = sb * 8;

    __shared__ float A[14][512];
    __shared__ float Bf[14][512];

    for (int r = 0; r < 14; ++r) {
        int gy = y0 - 3 + r;
        for (int xx = t; xx < 512; xx += 256) {
            float v = 0.f;
            if (gy >= 0 && gy < H) v = sc[(size_t)b * HW + (size_t)gy * W + xx];
            A[r][xx] = v;
        }
    }
    __syncthreads();
    for (int r = 0; r < 14; ++r)
        for (int xx = t; xx < 512; xx += 256) {
            float s = 0.f;
            #pragma unroll
            for (int d = -2; d <= 2; ++d) {
                int x2 = xx + d;
                if (x2 >= 0 && x2 < 512) s += A[r][x2];
            }
            Bf[r][xx] = s;
        }
    __syncthreads();
    for (int r2 = 0; r2 < 10; ++r2) {
        int gy = y0 - 1 + r2;
        for (int xx = t; xx < 512; xx += 256) {
            float s = 0.f;
            if (gy >= 0 && gy < H) {
                #pragma unroll
                for (int d = 0; d < 5; ++d) s += Bf[r2 + d][xx];
                s *= (1.f / 25.f);
            }
            A[r2][xx] = s;
        }
    }
    __syncthreads();
    for (int r2 = 0; r2 < 10; ++r2)
        for (int xx = t; xx < 512; xx += 256) {
            float s = 0.f;
            #pragma unroll
            for (int d = -1; d <= 1; ++d) {
                int x2 = xx + d;
                if (x2 >= 0 && x2 < 512) s += A[r2][x2];
            }
            Bf[r2][xx] = s;
        }
    __syncthreads();

    float top[10];
    #pragma unroll
    for (int k = 0; k < 10; ++k) top[k] = -INFINITY;

    for (int r3 = 0; r3 < 8; ++r3) {
        for (int xx = t; xx < 512; xx += 256) {
            float sv = (Bf[r3][xx] + Bf[r3 + 1][xx] + Bf[r3 + 2][xx]) * (1.f / 9.f);
            score_map[(size_t)b * HW + (size_t)(y0 + r3) * W + xx] = sv;
            float s = 1.f / (1.f + expf(-sv));
            if (s > top[9]) {
                top[9] = s;
                #pragma unroll
                for (int k = 9; k > 0; --k)
                    if (top[k] > top[k - 1]) { float tmp = top[k - 1]; top[k - 1] = top[k]; top[k] = tmp; }
            }
        }
    }

    __shared__ float sv_[256];
    __shared__ int   si_[256];
    __shared__ int   swin;
    int ptr = 0;
    for (int r = 0; r < 10; ++r) {
        sv_[t] = (ptr < 10) ? top[ptr] : -INFINITY;
        si_[t] = t;
        __syncthreads();
        for (int off = 128; off > 0; off >>= 1) {
            if (t < off && sv_[t + off] > sv_[t]) { sv_[t] = sv_[t + off]; si_[t] = si_[t + off]; }
            __syncthreads();
        }
        if (t == 0) { cand[((size_t)b * 64 + sb) * 10 + r] = sv_[0]; swin = si_[0]; }
        __syncthreads();
        if (t == swin) ptr++;
        __syncthreads();
    }
}

// ---------------- 10th-largest over 640 candidates (tie-robust rank count) ----------------
__global__ __launch_bounds__(256) void k_v10(const float* __restrict__ cand, float* __restrict__ v10) {
    int b = blockIdx.x, t = threadIdx.x;
    __shared__ float c[640];
    for (int j = t; j < 640; j += 256) c[j] = cand[b * 640 + j];
    __syncthreads();
    for (int j = t; j < 640; j += 256) {
        float v = c[j];
        int gt = 0, eq = 0;
        for (int k = 0; k < 640; ++k) { gt += (c[k] > v); eq += (c[k] == v); }
        if (gt <= 9 && gt + eq >= 10) v10[b] = v;
    }
}

// ---------------- final decode (max over 4 partial pw buffers) ----------------
// NOTE: first arg MUST be the POOLED score_map (R11 bug: passed raw sc -> absmax 748).
__global__ __launch_bounds__(256) void k_final(const float* __restrict__ smap,
                                               const float* __restrict__ pw,
                                               const float* __restrict__ v10,
                                               float* __restrict__ outbuf,
                                               float* __restrict__ mbuf) {
    int p = blockIdx.x * 256 + threadIdx.x;
    if (p >= NB * HW) return;
    int b = p / HW, i = p % HW;
    float scv = smap[p];
    float s   = 1.f / (1.f + expf(-scv));          // same formula as k_poolcand -> identical bits
    float s10 = v10[b];
    bool  m   = (s >= s10 && s > 0.6f) || (s > 0.9f);
    size_t idx = (size_t)b * HW + i;
    float wmv = fmaxf(fmaxf(pw[idx], pw[(size_t)NB * HW + idx]),
                      fmaxf(pw[(size_t)2 * NB * HW + idx], pw[(size_t)3 * NB * HW + idx]));
    // reference quirk: w = channel0 (score_map), h = channel1 (wmax)
    float wv = expf(scv) * 10.f;
    float hv = expf(wmv) * 10.f;
    float xs = (float)(i & (W - 1));
    float ys = (float)(i >> 9);
    float o0 = 0.f, o1 = 0.f, o2 = 0.f, o3 = 0.f, o4 = 0.f;
    if (m) {
        o0 = s;
        o1 = floorf(xs - wv);
        o2 = floorf(ys - hv);
        o3 = ceilf(xs + wv);
        o4 = ceilf(ys + hv);
    }
    size_t ob = (size_t)p * 5;
    outbuf[ob + 0] = o0; outbuf[ob + 1] = o1; outbuf[ob + 2] = o2;
    outbuf[ob + 3] = o3; outbuf[ob + 4] = o4;
    mbuf[p] = m ? 1.f : 0.f;
}

extern "C" void kernel_launch(void* const* d_in, const int* in_sizes, int n_in,
                              void* d_out, int out_size, void* d_ws, size_t ws_size,
                              hipStream_t stream) {
    // inputs: mask (unused), color, w_bbx, w_score
    const float* color  = (const float*)d_in[1];
    const float* wbbx   = (const float*)d_in[2];
    const float* wscore = (const float*)d_in[3];

    float* out       = (float*)d_out;
    float* score_map = out;                          // 1048576
    float* outbuf    = out + 1048576;                // 5242880
    float* mbuf      = out + 1048576 + 5242880;      // 1048576

    float* ws   = (float*)d_ws;
    float* pw   = ws;                                // 4 groups x NB*HW = 16 MB
    float* sc   = ws + (size_t)4 * NB * HW;          // NB*HW = 4 MB
    float* cand = ws + (size_t)5 * NB * HW;          // 4*640
    float* v10  = cand + 2560;                       // 4

    k_sc       <<<(NB * HW / 4 + 255) / 256, 256, 0, stream>>>(color, wscore, sc);
    k_whmax    <<<dim3(4, 16, NB * 4), 256, 0, stream>>>(color, wbbx, pw);
    k_poolcand <<<dim3(64, NB), 256, 0, stream>>>(sc, score_map, cand);
    k_v10      <<<4, 256, 0, stream>>>(cand, v10);
    k_final    <<<(NB * HW + 255) / 256, 256, 0, stream>>>(score_map, pw, v10, outbuf, mbuf);
}

// Round 14
// 121.743 us; speedup vs baseline: 2.7757x; 1.1413x over previous
//
#include <hip/hip_runtime.h>
#include <math.h>

#define H 512
#define W 512
#define HW (H*W)
#define NB 4
#define NC 32

// ---- fused: [8 channels/group] score-conv partial + avgpool3x3 -> conv5x5 -> even max ----
// Group g handles channels 8g..8g+7. Even channels (4): LDS-staged pool+conv+max partial,
// plus sc contribution read from the staged tile center. Odd channels (4): direct center
// float4 reads (always in-bounds), independent loads that fill latency slack.
// Outputs: pw[g] (partial even-max), scE[g] (partial score conv). Color read EXACTLY once.
__global__ __launch_bounds__(256) void k_whmax_sc(const float* __restrict__ color,
                                                  const float* __restrict__ wbbx,
                                                  const float* __restrict__ wscore,
                                                  float* __restrict__ pw,
                                                  float* __restrict__ scE) {
    __shared__ float A[38][140];   // rows Y0-3..Y0+34, cols X0-4..X0+135
    __shared__ float P[36][136];   // rows Y0-2..Y0+33, cols X0-2..X0+133

    const int t  = threadIdx.x;
    const int X0 = blockIdx.x * 128;
    const int Y0 = blockIdx.y * 32;
    const int b  = blockIdx.z >> 2;
    const int g  = blockIdx.z & 3;
    const int tx = t & 31, ty = t >> 5;          // thread owns 4x4 outputs at (ty*4+ol, tx*4+cc)

    float wmx[4][4], scacc[4][4];
    #pragma unroll
    for (int ol = 0; ol < 4; ++ol)
        #pragma unroll
        for (int cc = 0; cc < 4; ++cc) { wmx[ol][cc] = -INFINITY; scacc[ol][cc] = 0.f; }

    for (int ci = 0; ci < 4; ++ci) {
        const int ce = 8 * g + 2 * ci;                       // even channel
        const int co = ce + 1;                               // odd channel
        const float* img = color + ((size_t)b * NC + ce) * HW;
        const float* imgO = color + ((size_t)b * NC + co) * HW;
        const float* wc  = wbbx + ce * 25;                   // uniform -> SGPR
        const float wse  = wscore[ce];
        const float wso  = wscore[co];

        // ---- stage A (zero-padded halo tile of even channel) ----
        for (int u = t; u < 38 * 35; u += 256) {
            int r = u / 35, c4 = u % 35;
            int gy = Y0 - 3 + r, gx0 = X0 - 4 + c4 * 4;
            float4 v = make_float4(0.f, 0.f, 0.f, 0.f);
            if (gy >= 0 && gy < H) {
                if (gx0 >= 0 && gx0 <= W - 4) {
                    v = *(const float4*)(img + (size_t)gy * W + gx0);
                } else {
                    float e0 = (gx0 + 0 >= 0 && gx0 + 0 < W) ? img[(size_t)gy * W + gx0 + 0] : 0.f;
                    float e1 = (gx0 + 1 >= 0 && gx0 + 1 < W) ? img[(size_t)gy * W + gx0 + 1] : 0.f;
                    float e2 = (gx0 + 2 >= 0 && gx0 + 2 < W) ? img[(size_t)gy * W + gx0 + 2] : 0.f;
                    float e3 = (gx0 + 3 >= 0 && gx0 + 3 < W) ? img[(size_t)gy * W + gx0 + 3] : 0.f;
                    v = make_float4(e0, e1, e2, e3);
                }
            }
            *(float4*)&A[r][c4 * 4] = v;
        }

        // ---- odd channel sc contribution: direct center reads (no LDS, no sync dep) ----
        #pragma unroll
        for (int ol = 0; ol < 4; ++ol) {
            float4 v = *(const float4*)(imgO + (size_t)(Y0 + ty * 4 + ol) * W + X0 + tx * 4);
            scacc[ol][0] = fmaf(v.x, wso, scacc[ol][0]);
            scacc[ol][1] = fmaf(v.y, wso, scacc[ol][1]);
            scacc[ol][2] = fmaf(v.z, wso, scacc[ol][2]);
            scacc[ol][3] = fmaf(v.w, wso, scacc[ol][3]);
        }

        __syncthreads();   // A ready; also guarantees prev iteration's phase3 (P readers) done

        // ---- even channel sc contribution from staged tile center ----
        #pragma unroll
        for (int ol = 0; ol < 4; ++ol) {
            float4 v = *(const float4*)&A[3 + ty * 4 + ol][4 + tx * 4];
            scacc[ol][0] = fmaf(v.x, wse, scacc[ol][0]);
            scacc[ol][1] = fmaf(v.y, wse, scacc[ol][1]);
            scacc[ol][2] = fmaf(v.z, wse, scacc[ol][2]);
            scacc[ol][3] = fmaf(v.w, wse, scacc[ol][3]);
        }

        // ---- phase 2: P = box3x3(A)/9, conv zero-padding folded ----
        for (int u = t; u < 36 * 17; u += 256) {
            int pr = u / 17, ch = u % 17;
            int j0 = ch * 8;
            int gyP = Y0 - 2 + pr;
            float p[8];
            if (gyP >= 0 && gyP < H) {
                float vs[12];
                #pragma unroll
                for (int q = 0; q < 3; ++q) {
                    float4 x0 = *(const float4*)&A[pr + 0][j0 + q * 4];
                    float4 x1 = *(const float4*)&A[pr + 1][j0 + q * 4];
                    float4 x2 = *(const float4*)&A[pr + 2][j0 + q * 4];
                    vs[q * 4 + 0] = x0.x + x1.x + x2.x;
                    vs[q * 4 + 1] = x0.y + x1.y + x2.y;
                    vs[q * 4 + 2] = x0.z + x1.z + x2.z;
                    vs[q * 4 + 3] = x0.w + x1.w + x2.w;
                }
                #pragma unroll
                for (int jj = 0; jj < 8; ++jj) {
                    int gxP = X0 - 2 + j0 + jj;
                    float s = (vs[jj + 1] + vs[jj + 2] + vs[jj + 3]) * (1.f / 9.f);
                    p[jj] = (gxP >= 0 && gxP < W) ? s : 0.f;
                }
            } else {
                #pragma unroll
                for (int jj = 0; jj < 8; ++jj) p[jj] = 0.f;
            }
            *(float4*)&P[pr][j0 + 0] = make_float4(p[0], p[1], p[2], p[3]);
            *(float4*)&P[pr][j0 + 4] = make_float4(p[4], p[5], p[6], p[7]);
        }
        __syncthreads();

        // ---- phase 3: conv5x5 from P (SGPR weights), fmax into wmx ----
        float acc[4][4];
        #pragma unroll
        for (int ol = 0; ol < 4; ++ol)
            #pragma unroll
            for (int cc = 0; cc < 4; ++cc) acc[ol][cc] = 0.f;

        #pragma unroll
        for (int pr8 = 0; pr8 < 8; ++pr8) {
            int pr = ty * 4 + pr8;
            float4 q0 = *(const float4*)&P[pr][tx * 4 + 0];
            float4 q1 = *(const float4*)&P[pr][tx * 4 + 4];
            float c8[8] = {q0.x, q0.y, q0.z, q0.w, q1.x, q1.y, q1.z, q1.w};
            #pragma unroll
            for (int ol = 0; ol < 4; ++ol) {
                const int ky = pr8 - ol;
                if (ky >= 0 && ky <= 4) {
                    #pragma unroll
                    for (int cc = 0; cc < 4; ++cc) {
                        float a = acc[ol][cc];
                        #pragma unroll
                        for (int kx = 0; kx < 5; ++kx)
                            a = fmaf(c8[cc + kx], wc[ky * 5 + kx], a);
                        acc[ol][cc] = a;
                    }
                }
            }
        }
        #pragma unroll
        for (int ol = 0; ol < 4; ++ol)
            #pragma unroll
            for (int cc = 0; cc < 4; ++cc)
                wmx[ol][cc] = fmaxf(wmx[ol][cc], acc[ol][cc]);
    }

    size_t off = ((size_t)g * NB + b) * HW + (size_t)(Y0 + ty * 4) * W + X0 + tx * 4;
    #pragma unroll
    for (int ol = 0; ol < 4; ++ol) {
        *(float4*)(pw  + off + (size_t)ol * W) = make_float4(wmx[ol][0], wmx[ol][1], wmx[ol][2], wmx[ol][3]);
        *(float4*)(scE + off + (size_t)ol * W) = make_float4(scacc[ol][0], scacc[ol][1], scacc[ol][2], scacc[ol][3]);
    }
}

// ---- fused: sum 4 sc partials -> avgpool5 -> avgpool3 -> sigmoid + per-stripe top10 ----
__global__ __launch_bounds__(256) void k_poolcand(const float* __restrict__ scE,
                                                  float* __restrict__ score_map,
                                                  float* __restrict__ cand) {
    const int sb = blockIdx.x;           // 0..63  (stripe)
    const int b  = blockIdx.y;
    const int t  = threadIdx.x;
    const int y0 = sb * 8;

    __shared__ float A[14][512];
    __shared__ float Bf[14][512];

    for (int r = 0; r < 14; ++r) {
        int gy = y0 - 3 + r;
        for (int xx = t; xx < 512; xx += 256) {
            float v = 0.f;
            if (gy >= 0 && gy < H) {
                size_t idx = (size_t)b * HW + (size_t)gy * W + xx;
                v = scE[idx] + scE[(size_t)NB * HW + idx]
                  + scE[(size_t)2 * NB * HW + idx] + scE[(size_t)3 * NB * HW + idx];
            }
            A[r][xx] = v;
        }
    }
    __syncthreads();
    for (int r = 0; r < 14; ++r)
        for (int xx = t; xx < 512; xx += 256) {
            float s = 0.f;
            #pragma unroll
            for (int d = -2; d <= 2; ++d) {
                int x2 = xx + d;
                if (x2 >= 0 && x2 < 512) s += A[r][x2];
            }
            Bf[r][xx] = s;
        }
    __syncthreads();
    for (int r2 = 0; r2 < 10; ++r2) {
        int gy = y0 - 1 + r2;
        for (int xx = t; xx < 512; xx += 256) {
            float s = 0.f;
            if (gy >= 0 && gy < H) {
                #pragma unroll
                for (int d = 0; d < 5; ++d) s += Bf[r2 + d][xx];
                s *= (1.f / 25.f);
            }
            A[r2][xx] = s;
        }
    }
    __syncthreads();
    for (int r2 = 0; r2 < 10; ++r2)
        for (int xx = t; xx < 512; xx += 256) {
            float s = 0.f;
            #pragma unroll
            for (int d = -1; d <= 1; ++d) {
                int x2 = xx + d;
                if (x2 >= 0 && x2 < 512) s += A[r2][x2];
            }
            Bf[r2][xx] = s;
        }
    __syncthreads();

    float top[10];
    #pragma unroll
    for (int k = 0; k < 10; ++k) top[k] = -INFINITY;

    for (int r3 = 0; r3 < 8; ++r3) {
        for (int xx = t; xx < 512; xx += 256) {
            float sv = (Bf[r3][xx] + Bf[r3 + 1][xx] + Bf[r3 + 2][xx]) * (1.f / 9.f);
            score_map[(size_t)b * HW + (size_t)(y0 + r3) * W + xx] = sv;
            float s = 1.f / (1.f + expf(-sv));
            if (s > top[9]) {
                top[9] = s;
                #pragma unroll
                for (int k = 9; k > 0; --k)
                    if (top[k] > top[k - 1]) { float tmp = top[k - 1]; top[k - 1] = top[k]; top[k] = tmp; }
            }
        }
    }

    __shared__ float sv_[256];
    __shared__ int   si_[256];
    __shared__ int   swin;
    int ptr = 0;
    for (int r = 0; r < 10; ++r) {
        sv_[t] = (ptr < 10) ? top[ptr] : -INFINITY;
        si_[t] = t;
        __syncthreads();
        for (int off = 128; off > 0; off >>= 1) {
            if (t < off && sv_[t + off] > sv_[t]) { sv_[t] = sv_[t + off]; si_[t] = si_[t + off]; }
            __syncthreads();
        }
        if (t == 0) { cand[((size_t)b * 64 + sb) * 10 + r] = sv_[0]; swin = si_[0]; }
        __syncthreads();
        if (t == swin) ptr++;
        __syncthreads();
    }
}

// ---- 10th-largest over 640 candidates (tie-robust rank count) ----
__global__ __launch_bounds__(256) void k_v10(const float* __restrict__ cand, float* __restrict__ v10) {
    int b = blockIdx.x, t = threadIdx.x;
    __shared__ float c[640];
    for (int j = t; j < 640; j += 256) c[j] = cand[b * 640 + j];
    __syncthreads();
    for (int j = t; j < 640; j += 256) {
        float v = c[j];
        int gt = 0, eq = 0;
        for (int k = 0; k < 640; ++k) { gt += (c[k] > v); eq += (c[k] == v); }
        if (gt <= 9 && gt + eq >= 10) v10[b] = v;
    }
}

// ---- final decode (max over 4 partial pw buffers; smap = POOLED score map) ----
__global__ __launch_bounds__(256) void k_final(const float* __restrict__ smap,
                                               const float* __restrict__ pw,
                                               const float* __restrict__ v10,
                                               float* __restrict__ outbuf,
                                               float* __restrict__ mbuf) {
    int p = blockIdx.x * 256 + threadIdx.x;
    if (p >= NB * HW) return;
    int b = p / HW, i = p % HW;
    float scv = smap[p];
    float s   = 1.f / (1.f + expf(-scv));          // same formula as k_poolcand -> identical bits
    float s10 = v10[b];
    bool  m   = (s >= s10 && s > 0.6f) || (s > 0.9f);
    size_t idx = (size_t)b * HW + i;
    float wmv = fmaxf(fmaxf(pw[idx], pw[(size_t)NB * HW + idx]),
                      fmaxf(pw[(size_t)2 * NB * HW + idx], pw[(size_t)3 * NB * HW + idx]));
    // reference quirk: w = channel0 (score_map), h = channel1 (wmax)
    float wv = expf(scv) * 10.f;
    float hv = expf(wmv) * 10.f;
    float xs = (float)(i & (W - 1));
    float ys = (float)(i >> 9);
    float o0 = 0.f, o1 = 0.f, o2 = 0.f, o3 = 0.f, o4 = 0.f;
    if (m) {
        o0 = s;
        o1 = floorf(xs - wv);
        o2 = floorf(ys - hv);
        o3 = ceilf(xs + wv);
        o4 = ceilf(ys + hv);
    }
    size_t ob = (size_t)p * 5;
    outbuf[ob + 0] = o0; outbuf[ob + 1] = o1; outbuf[ob + 2] = o2;
    outbuf[ob + 3] = o3; outbuf[ob + 4] = o4;
    mbuf[p] = m ? 1.f : 0.f;
}

extern "C" void kernel_launch(void* const* d_in, const int* in_sizes, int n_in,
                              void* d_out, int out_size, void* d_ws, size_t ws_size,
                              hipStream_t stream) {
    // inputs: mask (unused), color, w_bbx, w_score
    const float* color  = (const float*)d_in[1];
    const float* wbbx   = (const float*)d_in[2];
    const float* wscore = (const float*)d_in[3];

    float* out       = (float*)d_out;
    float* score_map = out;                          // 1048576
    float* outbuf    = out + 1048576;                // 5242880
    float* mbuf      = out + 1048576 + 5242880;      // 1048576

    float* ws   = (float*)d_ws;
    float* pw   = ws;                                // 4 planes x NB*HW = 16 MB
    float* scE  = ws + (size_t)4 * NB * HW;          // 4 planes x NB*HW = 16 MB
    float* cand = ws + (size_t)8 * NB * HW;          // 4*640
    float* v10  = cand + 2560;                       // 4

    k_whmax_sc <<<dim3(4, 16, NB * 4), 256, 0, stream>>>(color, wbbx, wscore, pw, scE);
    k_poolcand <<<dim3(64, NB), 256, 0, stream>>>(scE, score_map, cand);
    k_v10      <<<4, 256, 0, stream>>>(cand, v10);
    k_final    <<<(NB * HW + 255) / 256, 256, 0, stream>>>(score_map, pw, v10, outbuf, mbuf);
}